// Round 1
// baseline (213.803 us; speedup 1.0000x reference)
//
#include <hip/hip_runtime.h>
#include <stdint.h>

// Problem constants (from reference setup_inputs): x is [B=8, L=131072, C=16] f32,
// values are exact integers in [0, 5). K=9, pad_l=3, pad_r=4 -> output length L-1.
constexpr int Bn   = 8;
constexpr int Ln   = 131072;
constexpr int Cn   = 16;
constexpr int Lout = Ln - 1;           // 131071 (pad_l+pad_r = K-2!)
constexpr int Tn   = 64;               // outputs per thread
constexpr int NCHUNK = (Lout + Tn - 1) / Tn;  // 2048

// increment word for packed 4x8-bit counts of values 1..4; v==0 -> 0.
__device__ __forceinline__ uint32_t inc_of(int v) {
    return (uint32_t)((1ull << (v * 8)) >> 8);
}

__global__ __launch_bounds__(256, 4)
void mop_kernel(const float* __restrict__ x, float* __restrict__ outp) {
    float* dens = outp + (size_t)Bn * Lout * Cn;

    int t     = blockIdx.x * 256 + threadIdx.x;
    int c     = t & (Cn - 1);            // lanes 0..15 -> consecutive channels (64B coalesced)
    int chunk = (t >> 4) & (NCHUNK - 1);
    int b     = t >> 15;                 // t / (16 * 2048)

    const float* xb = x    + ((size_t)b * Ln)   * Cn + c;
    float*       ob = outp + ((size_t)b * Lout) * Cn + c;
    float*       db = dens + ((size_t)b * Lout) * Cn + c;
    int l0 = chunk * Tn;

    // Window for output l covers original positions [l-3, l+5].
    uint32_t cnt  = 0;   // 4x8-bit counts for values 1..4
    uint32_t hist = 0;   // 9 x 3-bit value history; oldest at bits [24:26]
    #pragma unroll
    for (int o = -3; o <= 5; ++o) {
        int p = l0 + o;
        int v = 0;
        if (p >= 0 && p < Ln) v = (int)xb[(size_t)p * Cn];
        hist = ((hist << 3) | (uint32_t)v) & 0x7FFFFFFu;
        cnt += inc_of(v);
    }

    for (int i = 0; i < Tn; ++i) {
        int l = l0 + i;

        int c1 = cnt & 255;
        int c2 = (cnt >> 8) & 255;
        int c3 = (cnt >> 16) & 255;
        int c4 = (cnt >> 24) & 255;
        int m  = max(max(c1, c2), max(c3, c4));

        // tie-averaged argmax over bins 1..4 (softmax@BETA=1e10 gives exactly 1/n per max bin)
        int n = (c1 == m) + (c2 == m) + (c3 == m) + (c4 == m);
        int s = (c1 == m) + 2 * (c2 == m) + 3 * (c3 == m) + 4 * (c4 == m);
        float ov = (m == 0) ? 0.0f : (float)s / (float)n;  // m==0 -> bin 0 wins alone
        float dv = (m == 0) ? 1.0f : (float)m;

        if (l < Lout) {
            ob[(size_t)l * Cn] = ov;
            db[(size_t)l * Cn] = dv;
        }

        // slide window: remove (l-3) from history, add (l+6)
        int vr = (hist >> 24) & 7;
        int pa = l + 6;
        int va = 0;
        if (pa < Ln) va = (int)xb[(size_t)pa * Cn];
        cnt += inc_of(va) - inc_of(vr);
        hist = ((hist << 3) | (uint32_t)va) & 0x7FFFFFFu;
    }
}

extern "C" void kernel_launch(void* const* d_in, const int* in_sizes, int n_in,
                              void* d_out, int out_size, void* d_ws, size_t ws_size,
                              hipStream_t stream) {
    const float* x = (const float*)d_in[0];
    float* outp = (float*)d_out;
    constexpr int total_threads = Bn * Cn * NCHUNK;  // 262144
    mop_kernel<<<total_threads / 256, 256, 0, stream>>>(x, outp);
}

// Round 2
// 200.488 us; speedup vs baseline: 1.0664x; 1.0664x over previous
//
#include <hip/hip_runtime.h>
#include <stdint.h>

// x: [B=8, L=131072, C=16] f32, integer values in [0,5). K=9, pad_l=3, pad_r=4
// -> output length L-1. Outputs (soft-argmax, density) each [B, L-1, C] f32,
// concatenated flat in d_out.
constexpr int Bn   = 8;
constexpr int Ln   = 131072;
constexpr int Cn   = 16;
constexpr int Lout = Ln - 1;                  // 131071
constexpr int Tn   = 16;                      // outputs per thread (per channel group)
constexpr int NCHUNK = (Lout + Tn - 1) / Tn;  // 8192
constexpr int CG   = Cn / 4;                  // 4 channel-groups of float4

// packed 4x8-bit count increment for values 1..4; v==0 -> 0. (64-bit shift so
// v=4 lands in byte 3 and v=0 underflows to 0 — single v_lshlrev_b64.)
__device__ __forceinline__ uint32_t inc_of(int v) {
    return (uint32_t)((1ull << (v * 8)) >> 8);
}

__global__ __launch_bounds__(256, 4)
void mop_kernel(const float4* __restrict__ x, float4* __restrict__ outp) {
    // x viewed as [B, L, CG] float4; outputs as [B, Lout, CG] float4 each.
    float4* dens = outp + (size_t)Bn * Lout * CG;

    int t     = blockIdx.x * 256 + threadIdx.x;
    int g     = t & (CG - 1);                 // 4 consecutive lanes = 16 channels = 64B line
    int chunk = (t >> 2) & (NCHUNK - 1);
    int b     = t >> 15;                      // / (CG * NCHUNK)

    const float4* xb = x    + ((size_t)b * Ln)   * CG + g;
    float4*       ob = outp + ((size_t)b * Lout) * CG + g;
    float4*       db = dens + ((size_t)b * Lout) * CG + g;
    int l0 = chunk * Tn;

    uint32_t cnt[4]  = {0, 0, 0, 0};   // per-channel packed counts of values 1..4
    uint32_t hist[4] = {0, 0, 0, 0};   // per-channel 9x3-bit value history

    // Window for output l covers original positions [l-3, l+5].
    #pragma unroll
    for (int o = -3; o <= 5; ++o) {
        int p = l0 + o;
        float4 vv = make_float4(0.f, 0.f, 0.f, 0.f);
        if (p >= 0 && p < Ln) vv = xb[(size_t)p * CG];
        int va[4] = {(int)vv.x, (int)vv.y, (int)vv.z, (int)vv.w};
        #pragma unroll
        for (int j = 0; j < 4; ++j) {
            cnt[j]  += inc_of(va[j]);
            hist[j]  = ((hist[j] << 3) | (uint32_t)va[j]) & 0x7FFFFFFu;
        }
    }

    #pragma unroll 4
    for (int i = 0; i < Tn; ++i) {
        int l = l0 + i;

        // issue next-window load early (address independent of loop state)
        int pa = l + 6;
        float4 vv = make_float4(0.f, 0.f, 0.f, 0.f);
        if (pa < Ln) vv = xb[(size_t)pa * CG];

        float ov[4], dv[4];
        #pragma unroll
        for (int j = 0; j < 4; ++j) {
            uint32_t cw = cnt[j];
            int c1 = cw & 255, c2 = (cw >> 8) & 255, c3 = (cw >> 16) & 255, c4 = cw >> 24;
            int m = max(max(c1, c2), max(c3, c4));
            // tie-averaged argmax over bins 1..4 (softmax@1e10 == 1/n per max bin)
            int n = (c1 == m) + (c2 == m) + (c3 == m) + (c4 == m);
            int s = (c1 == m) + 2 * (c2 == m) + 3 * (c3 == m) + 4 * (c4 == m);
            float r = __builtin_amdgcn_rcpf((float)n);   // exact for 1,2,4; ~1e-7 for 3
            ov[j] = (m == 0) ? 0.0f : (float)s * r;
            dv[j] = (m == 0) ? 1.0f : (float)m;
        }

        if (l < Lout) {
            ob[(size_t)l * CG] = make_float4(ov[0], ov[1], ov[2], ov[3]);
            db[(size_t)l * CG] = make_float4(dv[0], dv[1], dv[2], dv[3]);
        }

        int va[4] = {(int)vv.x, (int)vv.y, (int)vv.z, (int)vv.w};
        #pragma unroll
        for (int j = 0; j < 4; ++j) {
            int vr = (hist[j] >> 24) & 7;
            cnt[j] += inc_of(va[j]) - inc_of(vr);
            hist[j] = ((hist[j] << 3) | (uint32_t)va[j]) & 0x7FFFFFFu;
        }
    }
}

extern "C" void kernel_launch(void* const* d_in, const int* in_sizes, int n_in,
                              void* d_out, int out_size, void* d_ws, size_t ws_size,
                              hipStream_t stream) {
    const float4* x = (const float4*)d_in[0];
    float4* outp = (float4*)d_out;
    constexpr int total_threads = Bn * CG * NCHUNK;  // 262144
    mop_kernel<<<total_threads / 256, 256, 0, stream>>>(x, outp);
}